// Round 7
// baseline (266.586 us; speedup 1.0000x reference)
//
#include <hip/hip_runtime.h>
#include <hip/hip_bf16.h>
#include <stdint.h>

typedef __bf16 bf16_t;
typedef __bf16 bf16x8 __attribute__((ext_vector_type(8)));
typedef __bf16 bf16x4 __attribute__((ext_vector_type(4)));
typedef float f32x4 __attribute__((ext_vector_type(4)));

#define AS1 __attribute__((address_space(1)))
#define AS3 __attribute__((address_space(3)))

static __device__ __forceinline__ void gload_lds16(const void* g, void* l) {
  __builtin_amdgcn_global_load_lds((const AS1 void*)g, (AS3 void*)l, 16, 0, 0);
}

// v_cvt_pk_bf16_f32: dst.lo = bf16(lo), dst.hi = bf16(hi)
static __device__ __forceinline__ uint32_t cvt_pk(float lo, float hi) {
  uint32_t r;
  asm("v_cvt_pk_bf16_f32 %0, %1, %2" : "=v"(r) : "v"(lo), "v"(hi));
  return r;
}

// ---------------- fp32 -> bf16 convert (vectorized x4) ----------------
__global__ void cvt_f32_bf16(const float* __restrict__ in, bf16_t* __restrict__ out, int n4) {
  int i = blockIdx.x * blockDim.x + threadIdx.x;
  if (i >= n4) return;
  float4 v = ((const float4*)in)[i];
  bf16x4 o;
  o[0] = (bf16_t)v.x; o[1] = (bf16_t)v.y; o[2] = (bf16_t)v.z; o[3] = (bf16_t)v.w;
  *(bf16x4*)(out + (size_t)i * 4) = o;
}

// ---------------- GEMM C = A(MxK) * B(NxK)^T, bf16 in, fp32 acc ----------------
// MODE 0: qkv epilogue. q: scaled 0.125, (bh,t,d). k: (bh,t,d).
//         v: TRANSPOSED (bh,d,t) with per-64-tile k-permutation sigma
//         (k bits [f|u|l4|c] -> pos bits [f|l4|u|c]) so flash PV fragments
//         are lane-local packs.
// MODE 1: proj epilogue (+bias, fp32 row-major out)
template<int MODE>
__global__ __launch_bounds__(256) void gemm_bt(
    const bf16_t* __restrict__ A, const bf16_t* __restrict__ Bw,
    const float* __restrict__ bias, void* __restrict__ Cout,
    int M, int N, int K)
{
  __shared__ bf16_t As[128 * 32];
  __shared__ bf16_t Bs[128 * 32];
  const int tid = threadIdx.x;
  const int wave = tid >> 6, lane = tid & 63;
  const int l15 = lane & 15, l4 = lane >> 4;
  const int m0 = blockIdx.y * 128, n0 = blockIdx.x * 128;
  const int wm = (wave >> 1) * 64, wn = (wave & 1) * 64;
  f32x4 acc[4][4] = {};

  const int r = tid >> 2;
  const int cb = (tid & 3) * 16;
  const char* gA0 = (const char*)(A + (size_t)(m0 + r) * K) + cb;
  const char* gA1 = (const char*)(A + (size_t)(m0 + 64 + r) * K) + cb;
  const char* gB0 = (const char*)(Bw + (size_t)(n0 + r) * K) + cb;
  const char* gB1 = (const char*)(Bw + (size_t)(n0 + 64 + r) * K) + cb;
  char* lA = (char*)As + tid * 16;
  char* lB = (char*)Bs + tid * 16;

  for (int k0 = 0; k0 < K; k0 += 32) {
    const size_t koff = (size_t)k0 * 2;
    gload_lds16(gA0 + koff, lA);
    gload_lds16(gA1 + koff, lA + 4096);
    gload_lds16(gB0 + koff, lB);
    gload_lds16(gB1 + koff, lB + 4096);
    __syncthreads();
    bf16x8 af[4], bfr[4];
#pragma unroll
    for (int mt = 0; mt < 4; ++mt)
      af[mt] = *(const bf16x8*)&As[(wm + mt * 16 + l15) * 32 + l4 * 8];
#pragma unroll
    for (int nt = 0; nt < 4; ++nt)
      bfr[nt] = *(const bf16x8*)&Bs[(wn + nt * 16 + l15) * 32 + l4 * 8];
#pragma unroll
    for (int mt = 0; mt < 4; ++mt)
#pragma unroll
      for (int nt = 0; nt < 4; ++nt)
        acc[mt][nt] = __builtin_amdgcn_mfma_f32_16x16x32_bf16(af[mt], bfr[nt], acc[mt][nt], 0, 0, 0);
    __syncthreads();
  }

  if (MODE == 0) {
    bf16_t* qkv = (bf16_t*)Cout;
#pragma unroll
    for (int mt = 0; mt < 4; ++mt) {
#pragma unroll
      for (int nt = 0; nt < 4; ++nt) {
        const int col = n0 + wn + nt * 16 + l15;
        const float bv = bias[col];
        const int which = col >> 10;
        const int c = col & 1023;
        const int head = c >> 6, d = c & 63;
#pragma unroll
        for (int i = 0; i < 4; ++i) {
          const int row = m0 + wm + mt * 16 + l4 * 4 + i;
          const int bb = row >> 11, t = row & 2047;
          const int bh2 = bb * 16 + head;
          float v = acc[mt][nt][i] + bv;
          size_t idx;
          if (which == 0) {
            v *= 0.125f;
            idx = ((size_t)(bh2 * 2048 + t) << 6) + d;
          } else if (which == 1) {
            idx = 8388608 + ((size_t)(bh2 * 2048 + t) << 6) + d;
          } else {
            const int ko = t & 63;
            const int pos = (ko & 0x20) | ((ko & 0x0C) << 1) | ((ko & 0x10) >> 2) | (ko & 3);
            idx = 16777216 + (size_t)(bh2 * 64 + d) * 2048 + (t & ~63) + pos;
          }
          qkv[idx] = (bf16_t)v;
        }
      }
    }
  } else {
    float* C = (float*)Cout;
#pragma unroll
    for (int mt = 0; mt < 4; ++mt) {
#pragma unroll
      for (int nt = 0; nt < 4; ++nt) {
        const int col = n0 + wn + nt * 16 + l15;
        const float bv = bias[col];
#pragma unroll
        for (int i = 0; i < 4; ++i) {
          const int row = m0 + wm + mt * 16 + l4 * 4 + i;
          C[(size_t)row * N + col] = acc[mt][nt][i] + bv;
        }
      }
    }
  }
}

// ---------------- causal flash attention, NO LDS, direct-from-L2 ---------
// grid: 1024 blocks, 256 thr. Mapping: xcd=flat&7, bh=xcd*8+(idx&7),
// qt=15-(idx>>3)  -> same-bh blocks colocate per XCD (K/V 512KB L2-resident,
// 8 bh = 4MB = full L2), long blocks dispatch first. Waves free-run (no
// barriers). Swapped-operand S^T=mfma(K,Q), in-lane softmax, lane-local
// cvt_pk pack for PV (V stored (bh,d,t) sigma-permuted by the QKV GEMM).
__global__ __launch_bounds__(256) void flash_attn(
    const bf16_t* __restrict__ Qg, const bf16_t* __restrict__ Kg,
    const bf16_t* __restrict__ VTg, bf16_t* __restrict__ Y)
{
  const int T = 2048, HS = 64;
  const int flat = blockIdx.x;
  const int xcd = flat & 7;
  const int idx = flat >> 3;
  const int qt = 15 - (idx >> 3);
  const int bh = xcd * 8 + (idx & 7);
  const int q0 = qt * 128;
  const size_t baseQ = (size_t)bh * T * HS;   // Q,K: (bh, t, d)
  const size_t baseV = (size_t)bh * HS * T;   // VT:  (bh, d, t) sigma-permuted

  const int tid = threadIdx.x;
  const int wave = tid >> 6, lane = tid & 63;
  const int l15 = lane & 15, l4 = lane >> 4;

  // Q fragments for 2 halves (rows q0+wave*32+l15 and +16)
  const bf16_t* qr = Qg + baseQ + (size_t)(q0 + wave * 32 + l15) * HS;
  const bf16x8 aq00 = *(const bf16x8*)(qr + l4 * 8);
  const bf16x8 aq01 = *(const bf16x8*)(qr + 32 + l4 * 8);
  const bf16x8 aq10 = *(const bf16x8*)(qr + 16 * HS + l4 * 8);
  const bf16x8 aq11 = *(const bf16x8*)(qr + 16 * HS + 32 + l4 * 8);

  float m0 = -1e30f, l0 = 0.f, m1 = -1e30f, l1 = 0.f;
  f32x4 o00 = {}, o01 = {}, o02 = {}, o03 = {};
  f32x4 o10 = {}, o11 = {}, o12 = {}, o13 = {};

  const int bound = 2 * qt + (wave >> 1);   // last kv-tile for this wave
  const int qb0 = (wave & 1) * 32 + l15;    // q offset within 64-row group
  const int qb1 = qb0 + 16;
  const int kb = l4 * 4;

  // per-lane fragment bases.
  // K frag (A-op): row = kt*64 + t*16 + l15, d = l4*8 (+32). t:+1024, kt:+4096
  const bf16_t* kp = Kg + baseQ + (size_t)l15 * HS + l4 * 8;
  // V frag (A-op): d-row = t*16 + l15, pos = kt*64 + l4*8 (+32). t:+32768, kt:+64
  const bf16_t* vp = VTg + baseV + (size_t)l15 * T + l4 * 8;

  for (int kt = 0; kt <= bound; ++kt) {
    const bool dg = (kt == bound);
    // ---- K fragments (shared by both halves) ----
    const bf16x8 kA0 = *(const bf16x8*)(kp + 0);
    const bf16x8 kB0 = *(const bf16x8*)(kp + 32);
    const bf16x8 kA1 = *(const bf16x8*)(kp + 1024);
    const bf16x8 kB1 = *(const bf16x8*)(kp + 1024 + 32);
    const bf16x8 kA2 = *(const bf16x8*)(kp + 2048);
    const bf16x8 kB2 = *(const bf16x8*)(kp + 2048 + 32);
    const bf16x8 kA3 = *(const bf16x8*)(kp + 3072);
    const bf16x8 kB3 = *(const bf16x8*)(kp + 3072 + 32);

    // ---- S^T = K * Q, both halves ----
    f32x4 s00 = {}, s01 = {}, s02 = {}, s03 = {};
    f32x4 s10 = {}, s11 = {}, s12 = {}, s13 = {};
    s00 = __builtin_amdgcn_mfma_f32_16x16x32_bf16(kA0, aq00, s00, 0, 0, 0);
    s00 = __builtin_amdgcn_mfma_f32_16x16x32_bf16(kB0, aq01, s00, 0, 0, 0);
    s01 = __builtin_amdgcn_mfma_f32_16x16x32_bf16(kA1, aq00, s01, 0, 0, 0);
    s01 = __builtin_amdgcn_mfma_f32_16x16x32_bf16(kB1, aq01, s01, 0, 0, 0);
    s02 = __builtin_amdgcn_mfma_f32_16x16x32_bf16(kA2, aq00, s02, 0, 0, 0);
    s02 = __builtin_amdgcn_mfma_f32_16x16x32_bf16(kB2, aq01, s02, 0, 0, 0);
    s03 = __builtin_amdgcn_mfma_f32_16x16x32_bf16(kA3, aq00, s03, 0, 0, 0);
    s03 = __builtin_amdgcn_mfma_f32_16x16x32_bf16(kB3, aq01, s03, 0, 0, 0);
    s10 = __builtin_amdgcn_mfma_f32_16x16x32_bf16(kA0, aq10, s10, 0, 0, 0);
    s10 = __builtin_amdgcn_mfma_f32_16x16x32_bf16(kB0, aq11, s10, 0, 0, 0);
    s11 = __builtin_amdgcn_mfma_f32_16x16x32_bf16(kA1, aq10, s11, 0, 0, 0);
    s11 = __builtin_amdgcn_mfma_f32_16x16x32_bf16(kB1, aq11, s11, 0, 0, 0);
    s12 = __builtin_amdgcn_mfma_f32_16x16x32_bf16(kA2, aq10, s12, 0, 0, 0);
    s12 = __builtin_amdgcn_mfma_f32_16x16x32_bf16(kB2, aq11, s12, 0, 0, 0);
    s13 = __builtin_amdgcn_mfma_f32_16x16x32_bf16(kA3, aq10, s13, 0, 0, 0);
    s13 = __builtin_amdgcn_mfma_f32_16x16x32_bf16(kB3, aq11, s13, 0, 0, 0);

    if (dg) {
#pragma unroll
      for (int i = 0; i < 4; ++i) {
        if (kb + i > qb0)      s00[i] = -1e30f;
        if (16 + kb + i > qb0) s01[i] = -1e30f;
        if (32 + kb + i > qb0) s02[i] = -1e30f;
        if (48 + kb + i > qb0) s03[i] = -1e30f;
        if (kb + i > qb1)      s10[i] = -1e30f;
        if (16 + kb + i > qb1) s11[i] = -1e30f;
        if (32 + kb + i > qb1) s12[i] = -1e30f;
        if (48 + kb + i > qb1) s13[i] = -1e30f;
      }
    }

    // ---- online softmax, in-lane (2 shuffles per half) ----
    union { uint32_t u[4]; bf16x8 v; } B00, B01, B10, B11;
    {
      float pm = fmaxf(fmaxf(fmaxf(s00[0], s00[1]), fmaxf(s00[2], s00[3])),
                       fmaxf(fmaxf(s01[0], s01[1]), fmaxf(s01[2], s01[3])));
      pm = fmaxf(pm, fmaxf(fmaxf(fmaxf(s02[0], s02[1]), fmaxf(s02[2], s02[3])),
                           fmaxf(fmaxf(s03[0], s03[1]), fmaxf(s03[2], s03[3]))));
      pm = fmaxf(pm, __shfl_xor(pm, 16));
      pm = fmaxf(pm, __shfl_xor(pm, 32));
      const float mn = fmaxf(m0, pm);
      const float sc = __expf(m0 - mn);
      m0 = mn;
#pragma unroll
      for (int i = 0; i < 4; ++i) {
        s00[i] = __expf(s00[i] - mn);
        s01[i] = __expf(s01[i] - mn);
        s02[i] = __expf(s02[i] - mn);
        s03[i] = __expf(s03[i] - mn);
      }
      float rs = ((s00[0] + s00[1]) + (s00[2] + s00[3])) + ((s01[0] + s01[1]) + (s01[2] + s01[3]))
               + ((s02[0] + s02[1]) + (s02[2] + s02[3])) + ((s03[0] + s03[1]) + (s03[2] + s03[3]));
      rs += __shfl_xor(rs, 16);
      rs += __shfl_xor(rs, 32);
      l0 = l0 * sc + rs;
      o00 *= sc; o01 *= sc; o02 *= sc; o03 *= sc;
      B00.u[0] = cvt_pk(s00[0], s00[1]); B00.u[1] = cvt_pk(s00[2], s00[3]);
      B00.u[2] = cvt_pk(s01[0], s01[1]); B00.u[3] = cvt_pk(s01[2], s01[3]);
      B01.u[0] = cvt_pk(s02[0], s02[1]); B01.u[1] = cvt_pk(s02[2], s02[3]);
      B01.u[2] = cvt_pk(s03[0], s03[1]); B01.u[3] = cvt_pk(s03[2], s03[3]);
    }
    {
      float pm = fmaxf(fmaxf(fmaxf(s10[0], s10[1]), fmaxf(s10[2], s10[3])),
                       fmaxf(fmaxf(s11[0], s11[1]), fmaxf(s11[2], s11[3])));
      pm = fmaxf(pm, fmaxf(fmaxf(fmaxf(s12[0], s12[1]), fmaxf(s12[2], s12[3])),
                           fmaxf(fmaxf(s13[0], s13[1]), fmaxf(s13[2], s13[3]))));
      pm = fmaxf(pm, __shfl_xor(pm, 16));
      pm = fmaxf(pm, __shfl_xor(pm, 32));
      const float mn = fmaxf(m1, pm);
      const float sc = __expf(m1 - mn);
      m1 = mn;
#pragma unroll
      for (int i = 0; i < 4; ++i) {
        s10[i] = __expf(s10[i] - mn);
        s11[i] = __expf(s11[i] - mn);
        s12[i] = __expf(s12[i] - mn);
        s13[i] = __expf(s13[i] - mn);
      }
      float rs = ((s10[0] + s10[1]) + (s10[2] + s10[3])) + ((s11[0] + s11[1]) + (s11[2] + s11[3]))
               + ((s12[0] + s12[1]) + (s12[2] + s12[3])) + ((s13[0] + s13[1]) + (s13[2] + s13[3]));
      rs += __shfl_xor(rs, 16);
      rs += __shfl_xor(rs, 32);
      l1 = l1 * sc + rs;
      o10 *= sc; o11 *= sc; o12 *= sc; o13 *= sc;
      B10.u[0] = cvt_pk(s10[0], s10[1]); B10.u[1] = cvt_pk(s10[2], s10[3]);
      B10.u[2] = cvt_pk(s11[0], s11[1]); B10.u[3] = cvt_pk(s11[2], s11[3]);
      B11.u[0] = cvt_pk(s12[0], s12[1]); B11.u[1] = cvt_pk(s12[2], s12[3]);
      B11.u[2] = cvt_pk(s13[0], s13[1]); B11.u[3] = cvt_pk(s13[2], s13[3]);
    }

    // ---- V fragments (shared by both halves) + PV ----
    const bf16x8 vA0 = *(const bf16x8*)(vp + 0);
    const bf16x8 vB0 = *(const bf16x8*)(vp + 32);
    const bf16x8 vA1 = *(const bf16x8*)(vp + 32768);
    const bf16x8 vB1 = *(const bf16x8*)(vp + 32768 + 32);
    const bf16x8 vA2 = *(const bf16x8*)(vp + 65536);
    const bf16x8 vB2 = *(const bf16x8*)(vp + 65536 + 32);
    const bf16x8 vA3 = *(const bf16x8*)(vp + 98304);
    const bf16x8 vB3 = *(const bf16x8*)(vp + 98304 + 32);

    o00 = __builtin_amdgcn_mfma_f32_16x16x32_bf16(vA0, B00.v, o00, 0, 0, 0);
    o00 = __builtin_amdgcn_mfma_f32_16x16x32_bf16(vB0, B01.v, o00, 0, 0, 0);
    o01 = __builtin_amdgcn_mfma_f32_16x16x32_bf16(vA1, B00.v, o01, 0, 0, 0);
    o01 = __builtin_amdgcn_mfma_f32_16x16x32_bf16(vB1, B01.v, o01, 0, 0, 0);
    o02 = __builtin_amdgcn_mfma_f32_16x16x32_bf16(vA2, B00.v, o02, 0, 0, 0);
    o02 = __builtin_amdgcn_mfma_f32_16x16x32_bf16(vB2, B01.v, o02, 0, 0, 0);
    o03 = __builtin_amdgcn_mfma_f32_16x16x32_bf16(vA3, B00.v, o03, 0, 0, 0);
    o03 = __builtin_amdgcn_mfma_f32_16x16x32_bf16(vB3, B01.v, o03, 0, 0, 0);
    o10 = __builtin_amdgcn_mfma_f32_16x16x32_bf16(vA0, B10.v, o10, 0, 0, 0);
    o10 = __builtin_amdgcn_mfma_f32_16x16x32_bf16(vB0, B11.v, o10, 0, 0, 0);
    o11 = __builtin_amdgcn_mfma_f32_16x16x32_bf16(vA1, B10.v, o11, 0, 0, 0);
    o11 = __builtin_amdgcn_mfma_f32_16x16x32_bf16(vB1, B11.v, o11, 0, 0, 0);
    o12 = __builtin_amdgcn_mfma_f32_16x16x32_bf16(vA2, B10.v, o12, 0, 0, 0);
    o12 = __builtin_amdgcn_mfma_f32_16x16x32_bf16(vB2, B11.v, o12, 0, 0, 0);
    o13 = __builtin_amdgcn_mfma_f32_16x16x32_bf16(vA3, B10.v, o13, 0, 0, 0);
    o13 = __builtin_amdgcn_mfma_f32_16x16x32_bf16(vB3, B11.v, o13, 0, 0, 0);

    kp += 4096;   // next 64 K-rows
    vp += 64;     // next 64 k-positions
  }

  // epilogue: O^T (d = t*16+l4*4+i, q = l15) -> Y (B,T,C) bf16, packed 8B
  const int b = bh >> 4, h = bh & 15;
  {
    const float il = 1.f / l0;
    const int q = q0 + wave * 32 + l15;
    bf16_t* yr = Y + ((size_t)(b * T + q)) * 1024 + h * 64 + l4 * 4;
    uint2 w;
    w.x = cvt_pk(o00[0] * il, o00[1] * il); w.y = cvt_pk(o00[2] * il, o00[3] * il);
    *(uint2*)(yr + 0) = w;
    w.x = cvt_pk(o01[0] * il, o01[1] * il); w.y = cvt_pk(o01[2] * il, o01[3] * il);
    *(uint2*)(yr + 16) = w;
    w.x = cvt_pk(o02[0] * il, o02[1] * il); w.y = cvt_pk(o02[2] * il, o02[3] * il);
    *(uint2*)(yr + 32) = w;
    w.x = cvt_pk(o03[0] * il, o03[1] * il); w.y = cvt_pk(o03[2] * il, o03[3] * il);
    *(uint2*)(yr + 48) = w;
  }
  {
    const float il = 1.f / l1;
    const int q = q0 + wave * 32 + 16 + l15;
    bf16_t* yr = Y + ((size_t)(b * T + q)) * 1024 + h * 64 + l4 * 4;
    uint2 w;
    w.x = cvt_pk(o10[0] * il, o10[1] * il); w.y = cvt_pk(o10[2] * il, o10[3] * il);
    *(uint2*)(yr + 0) = w;
    w.x = cvt_pk(o11[0] * il, o11[1] * il); w.y = cvt_pk(o11[2] * il, o11[3] * il);
    *(uint2*)(yr + 16) = w;
    w.x = cvt_pk(o12[0] * il, o12[1] * il); w.y = cvt_pk(o12[2] * il, o12[3] * il);
    *(uint2*)(yr + 32) = w;
    w.x = cvt_pk(o13[0] * il, o13[1] * il); w.y = cvt_pk(o13[2] * il, o13[3] * il);
    *(uint2*)(yr + 48) = w;
  }
}

// ---------------- launch ----------------
extern "C" void kernel_launch(void* const* d_in, const int* in_sizes, int n_in,
                              void* d_out, int out_size, void* d_ws, size_t ws_size,
                              hipStream_t stream) {
  const float* x      = (const float*)d_in[0];
  const float* w_attn = (const float*)d_in[1];
  const float* b_attn = (const float*)d_in[2];
  const float* w_proj = (const float*)d_in[3];
  const float* b_proj = (const float*)d_in[4];
  float* out = (float*)d_out;

  char* ws = (char*)d_ws;
  bf16_t* xb   = (bf16_t*)(ws);
  bf16_t* wab  = (bf16_t*)(ws + 16777216);
  bf16_t* wpb  = (bf16_t*)(ws + 23068672);
  bf16_t* qkvb = (bf16_t*)(ws + 25165824);   // q | k | vT (8M elems each)
  bf16_t* yb   = (bf16_t*)(ws + 75497472);

  cvt_f32_bf16<<<8192, 256, 0, stream>>>(x, xb, 2097152);
  cvt_f32_bf16<<<3072, 256, 0, stream>>>(w_attn, wab, 786432);
  cvt_f32_bf16<<<1024, 256, 0, stream>>>(w_proj, wpb, 262144);

  dim3 g1(24, 64);
  gemm_bt<0><<<g1, 256, 0, stream>>>(xb, wab, b_attn, (void*)qkvb, 8192, 3072, 1024);

  flash_attn<<<1024, 256, 0, stream>>>(qkvb, qkvb + 8388608, qkvb + 16777216, yb);

  dim3 g3(8, 64);
  gemm_bt<1><<<g3, 256, 0, stream>>>(yb, wpb, b_proj, (void*)out, 8192, 1024, 1024);
}